// Round 3
// baseline (256.968 us; speedup 1.0000x reference)
//
#include <hip/hip_runtime.h>

typedef unsigned short ushort_t;
typedef __attribute__((ext_vector_type(8))) short bf16x8;     // 8 bf16 in 4 VGPRs
typedef __attribute__((ext_vector_type(4))) float f32x4;
typedef __attribute__((ext_vector_type(16))) float f32x16;

__device__ __forceinline__ unsigned short f2bf(float f) {
    union { float f; unsigned u; } v; v.f = f;
    unsigned r = v.u + 0x7FFFu + ((v.u >> 16) & 1u);   // RNE
    return (unsigned short)(r >> 16);
}

// v_cvt_pk_bf16_f32: lo=RNE(a), hi=RNE(b) — bit-identical to f2bf, 1 inst / 2 elems
__device__ __forceinline__ unsigned cvt_pk_bf16(float a, float b) {
    unsigned r;
    asm("v_cvt_pk_bf16_f32 %0, %1, %2" : "=v"(r) : "v"(a), "v"(b));
    return r;
}

// ================= weight prep, fragment-major, coalesced writes =================
// B-fragment layout for v_mfma_f32_32x32x16_bf16: lane = khalf*32 + r32 holds
// W[ngrp*32 + r32][kfrag*16 + khalf*8 .. +8).  Stored as
//   Wf[(ngrp*KFRAGS + kfrag)*512 + lane*8 + e]
// W1eff folds the 3x3 conv into fc1 (p indexes the 28x28 input, zero-padded to 832).
__global__ __launch_bounds__(256) void prep_w(const float* __restrict__ fc1_w,
                                              const float* __restrict__ cw,
                                              const float* __restrict__ fc2_w,
                                              const float* __restrict__ out_w,
                                              ushort_t* __restrict__ W1,
                                              ushort_t* __restrict__ W2,
                                              ushort_t* __restrict__ W3) {
    const int idx = blockIdx.x * 256 + threadIdx.x;
    // ---- W1f: 16 ngrps x 52 kfrags x 512 = 425984 elements ----
    if (idx < 425984) {
        const int ngrp = idx / 26624;              // 52*512
        const int kfrag = (idx % 26624) >> 9;
        const int li = idx & 511;
        const int lane = li >> 3, e = li & 7;
        const int n = ngrp * 32 + (lane & 31);
        const int p = kfrag * 16 + (lane >> 5) * 8 + e;
        float acc = 0.f;
        if (p < 784) {
            const int pr = p / 28, pc = p % 28;
#pragma unroll
            for (int dr = 0; dr < 3; ++dr) {
                const int r = pr - dr;
                if (r < 0 || r >= 26) continue;
#pragma unroll
                for (int dc = 0; dc < 3; ++dc) {
                    const int col = pc - dc;
                    if (col < 0 || col >= 26) continue;
                    acc += cw[dr * 3 + dc] * fc1_w[n * 676 + r * 26 + col];
                }
            }
        }
        W1[idx] = f2bf(acc);
    }
    // ---- W2f: 16 ngrps x 32 kfrags x 512 = 262144 ----
    if (idx < 262144) {
        const int ngrp = idx / 16384;              // 32*512
        const int kfrag = (idx % 16384) >> 9;
        const int li = idx & 511;
        const int lane = li >> 3, e = li & 7;
        const int n = ngrp * 32 + (lane & 31);
        const int p = kfrag * 16 + (lane >> 5) * 8 + e;
        W2[idx] = f2bf(fc2_w[n * 512 + p]);
    }
    if (idx < 16 * 512)  W3[idx] = (idx < 10 * 512) ? f2bf(out_w[idx]) : (ushort_t)0;
}

// ================= fully-fused network, v7: barrier-free phase 1 =================
// 256 blocks x 128 batch rows, 1024 threads (16 waves, 4/SIMD). Wave (wm,wn) owns a
// 64x64 tile: rows wm*64.., n-groups {2wn, 2wn+1}. acc[2][2]=64 AGPR + <=64 VGPR keeps
// 4 waves/SIMD.
// Phase 1 loads A-fragments DIRECTLY from global x (2 dwordx4/frag, row base + imm
// offsets; lanes r32 / r32+32 share a 64B line; the 16KB x-slice is L1-resident across
// the 8 waves sharing it) and converts via v_cvt_pk_bf16_f32. No x staging, no LDS
// reads, and NO BARRIERS in phase 1 -> waves free-run, VMEM/LDS/MFMA overlap.
// hs [128][512] = 128KB LDS holds h1/h2 only. 3 barriers total in the kernel.
__global__ __launch_bounds__(1024, 4) void mega7(const float* __restrict__ x,
                                                 const ushort_t* __restrict__ W1,
                                                 const ushort_t* __restrict__ W2,
                                                 const ushort_t* __restrict__ W3,
                                                 const float* __restrict__ b1,
                                                 const float* __restrict__ b2,
                                                 const float* __restrict__ ob,
                                                 float* __restrict__ out) {
    extern __shared__ ushort_t smem[];
    ushort_t* hs = smem;                 // [128][512] 128 KB h1/h2 tile (seg-swizzled)

    const int tid = threadIdx.x;
    const int wave = tid >> 6, lane = tid & 63;
    const int r32 = lane & 31, khalf = lane >> 5;
    const int wm = wave >> 3;                           // m-half (0/1)
    const int wn = wave & 7;                            // n-pair index
    const size_t ng0 = wn * 2, ng1 = wn * 2 + 1;        // this wave's two n-groups
    const int m0 = blockIdx.x * 128;

    // row bases for the two 32-row A fragments (khalf picks the k-half of each frag)
    const float* xr0 = x + (size_t)(m0 + wm * 64 + r32) * 784 + khalf * 8;
    const float* xr1 = xr0 + (size_t)32 * 784;

    f32x16 acc[2][2];                                   // [i = m-frag][j = ngrp]
#pragma unroll
    for (int a = 0; a < 2; ++a)
#pragma unroll
        for (int j = 0; j < 2; ++j)
#pragma unroll
            for (int e = 0; e < 16; ++e) acc[a][j][e] = 0.f;

    // A-fragment straight from global: 2 x dwordx4 + 4 x v_cvt_pk_bf16_f32
    auto mk_af = [&](const float* xr, int kf) -> bf16x8 {
        const f32x4 a = *(const f32x4*)(xr + kf * 16);
        const f32x4 b = *(const f32x4*)(xr + kf * 16 + 4);
        union { bf16x8 h; unsigned u[4]; } r;
        r.u[0] = cvt_pk_bf16(a.x, a.y);
        r.u[1] = cvt_pk_bf16(a.z, a.w);
        r.u[2] = cvt_pk_bf16(b.x, b.y);
        r.u[3] = cvt_pk_bf16(b.z, b.w);
        return r.h;
    };

    // h-epilogue: bias+relu -> hs (A-layout, seg' = seg ^ (m&7)); cols = this wave's 64 n
    auto write_h = [&](const float* __restrict__ bias) {
#pragma unroll
        for (int j = 0; j < 2; ++j) {
            const int n = (wn * 2 + j) * 32 + r32;
            const float bb = bias[n];
            const int nseg = n >> 3, nrem = n & 7;
#pragma unroll
            for (int i = 0; i < 2; ++i)
#pragma unroll
                for (int reg = 0; reg < 16; ++reg) {
                    const int m = wm * 64 + i * 32 + 4 * khalf + (reg & 3) + 8 * (reg >> 2);
                    hs[m * 512 + ((nseg ^ (m & 7)) * 8) + nrem] = f2bf(fmaxf(acc[i][j][reg] + bb, 0.f));
                }
        }
    };

    // ---------------- phase 1: kfrag 0..48 (k 784..831 is zero pad -> skipped), NO barriers ----
    for (int ks = 0; ks < 12; ++ks) {
#pragma unroll
        for (int ksub = 0; ksub < 4; ++ksub) {
            const int kf = ks * 4 + ksub;
            const bf16x8 bw0 = *(const bf16x8*)&W1[(ng0 * 52 + kf) * 512 + lane * 8];
            const bf16x8 bw1 = *(const bf16x8*)&W1[(ng1 * 52 + kf) * 512 + lane * 8];
            const bf16x8 af0 = mk_af(xr0, kf);
            const bf16x8 af1 = mk_af(xr1, kf);
            __builtin_amdgcn_s_setprio(1);
            acc[0][0] = __builtin_amdgcn_mfma_f32_32x32x16_bf16(af0, bw0, acc[0][0], 0, 0, 0);
            acc[0][1] = __builtin_amdgcn_mfma_f32_32x32x16_bf16(af0, bw1, acc[0][1], 0, 0, 0);
            acc[1][0] = __builtin_amdgcn_mfma_f32_32x32x16_bf16(af1, bw0, acc[1][0], 0, 0, 0);
            acc[1][1] = __builtin_amdgcn_mfma_f32_32x32x16_bf16(af1, bw1, acc[1][1], 0, 0, 0);
            __builtin_amdgcn_s_setprio(0);
        }
    }
    {   // tail: kfrag 48 (cols 768..783, all real)
        const int kf = 48;
        const bf16x8 bw0 = *(const bf16x8*)&W1[(ng0 * 52 + kf) * 512 + lane * 8];
        const bf16x8 bw1 = *(const bf16x8*)&W1[(ng1 * 52 + kf) * 512 + lane * 8];
        const bf16x8 af0 = mk_af(xr0, kf);
        const bf16x8 af1 = mk_af(xr1, kf);
        __builtin_amdgcn_s_setprio(1);
        acc[0][0] = __builtin_amdgcn_mfma_f32_32x32x16_bf16(af0, bw0, acc[0][0], 0, 0, 0);
        acc[0][1] = __builtin_amdgcn_mfma_f32_32x32x16_bf16(af0, bw1, acc[0][1], 0, 0, 0);
        acc[1][0] = __builtin_amdgcn_mfma_f32_32x32x16_bf16(af1, bw0, acc[1][0], 0, 0, 0);
        acc[1][1] = __builtin_amdgcn_mfma_f32_32x32x16_bf16(af1, bw1, acc[1][1], 0, 0, 0);
        __builtin_amdgcn_s_setprio(0);
    }

    // ---- h1 = relu(acc + b1) -> hs ----
    write_h(b1);
#pragma unroll
    for (int a = 0; a < 2; ++a)
#pragma unroll
        for (int j = 0; j < 2; ++j)
#pragma unroll
            for (int e = 0; e < 16; ++e) acc[a][j][e] = 0.f;
    __syncthreads();

    // ---------------- phase 2: K = 512, no intra-phase barriers ----------------
    for (int ks = 0; ks < 8; ++ks) {
#pragma unroll
        for (int ksub = 0; ksub < 4; ++ksub) {
            const int kf = ks * 4 + ksub;
            const bf16x8 bw0 = *(const bf16x8*)&W2[(ng0 * 32 + kf) * 512 + lane * 8];
            const bf16x8 bw1 = *(const bf16x8*)&W2[(ng1 * 32 + kf) * 512 + lane * 8];
            const int hq = kf * 2 + khalf;              // 16B-seg index within hs row (0..63)
            bf16x8 af[2];
#pragma unroll
            for (int i = 0; i < 2; ++i) {
                const int m = wm * 64 + i * 32 + r32;
                af[i] = *(const bf16x8*)&hs[m * 512 + ((hq ^ (m & 7)) * 8)];
            }
            __builtin_amdgcn_s_setprio(1);
            acc[0][0] = __builtin_amdgcn_mfma_f32_32x32x16_bf16(af[0], bw0, acc[0][0], 0, 0, 0);
            acc[0][1] = __builtin_amdgcn_mfma_f32_32x32x16_bf16(af[0], bw1, acc[0][1], 0, 0, 0);
            acc[1][0] = __builtin_amdgcn_mfma_f32_32x32x16_bf16(af[1], bw0, acc[1][0], 0, 0, 0);
            acc[1][1] = __builtin_amdgcn_mfma_f32_32x32x16_bf16(af[1], bw1, acc[1][1], 0, 0, 0);
            __builtin_amdgcn_s_setprio(0);
        }
    }
    __syncthreads();                                    // all hs(h1) reads done

    // ---- h2 = relu(acc + b2) -> hs ----
    write_h(b2);
    __syncthreads();

    // ---------------- head: waves 0..7 -> 16 rows each, K=512, direct stores ----------------
    if (wave < 8) {
        const int quad = lane >> 4, l16 = lane & 15;
        const int row = wave * 16 + l16;
        f32x4 hacc = {0.f, 0.f, 0.f, 0.f};
#pragma unroll
        for (int ks = 0; ks < 16; ++ks) {
            const int seg = 4 * ks + quad;
            const bf16x8 a = *(const bf16x8*)&hs[row * 512 + ((seg ^ (row & 7)) * 8)];
            const bf16x8 b = *(const bf16x8*)&W3[l16 * 512 + ks * 32 + quad * 8];
            hacc = __builtin_amdgcn_mfma_f32_16x16x32_bf16(a, b, hacc, 0, 0, 0);
        }
        if (l16 < 10) {
            const float bb = ob[l16];
#pragma unroll
            for (int r = 0; r < 4; ++r)
                out[(size_t)(m0 + wave * 16 + quad * 4 + r) * 10 + l16] = hacc[r] + bb;
        }
    }
}

extern "C" void kernel_launch(void* const* d_in, const int* in_sizes, int n_in,
                              void* d_out, int out_size, void* d_ws, size_t ws_size,
                              hipStream_t stream) {
    const float* x      = (const float*)d_in[0];
    const float* conv_w = (const float*)d_in[1];
    const float* fc1_w  = (const float*)d_in[2];
    const float* fc1_b  = (const float*)d_in[3];
    const float* fc2_w  = (const float*)d_in[4];
    const float* fc2_b  = (const float*)d_in[5];
    const float* out_w  = (const float*)d_in[6];
    const float* out_b  = (const float*)d_in[7];
    float* out = (float*)d_out;

    // workspace: W1f | W2f | W3 (≈1.4 MB total), fragment-major layouts
    ushort_t* W1 = (ushort_t*)d_ws;                    // 16*52*512
    ushort_t* W2 = W1 + 425984;                        // 16*32*512
    ushort_t* W3 = W2 + 262144;                        // 16*512

    prep_w<<<dim3(1664), 256, 0, stream>>>(fc1_w, conv_w, fc2_w, out_w, W1, W2, W3);

    // 256 blocks x 128 rows; 1024 threads (16 waves, 4/SIMD); 128 KB dynamic LDS
    mega7<<<dim3(256), 1024, 131072, stream>>>(x, W1, W2, W3, fc1_b, fc2_b, out_b, out);
}

// Round 4
// 218.740 us; speedup vs baseline: 1.1748x; 1.1748x over previous
//
#include <hip/hip_runtime.h>

typedef unsigned short ushort_t;
typedef __attribute__((ext_vector_type(8))) short bf16x8;     // 8 bf16 in 4 VGPRs
typedef __attribute__((ext_vector_type(4))) float f32x4;
typedef __attribute__((ext_vector_type(16))) float f32x16;

__device__ __forceinline__ unsigned short f2bf(float f) {
    union { float f; unsigned u; } v; v.f = f;
    unsigned r = v.u + 0x7FFFu + ((v.u >> 16) & 1u);   // RNE
    return (unsigned short)(r >> 16);
}

// ================= weight prep, fragment-major, coalesced writes =================
// B-fragment layout for v_mfma_f32_32x32x16_bf16: lane = khalf*32 + r32 holds
// W[ngrp*32 + r32][kfrag*16 + khalf*8 .. +8).  Stored as
//   Wf[(ngrp*KFRAGS + kfrag)*512 + lane*8 + e]
// W1eff folds the 3x3 conv into fc1 (p indexes the 28x28 input, zero-padded to 832).
__global__ __launch_bounds__(256) void prep_w(const float* __restrict__ fc1_w,
                                              const float* __restrict__ cw,
                                              const float* __restrict__ fc2_w,
                                              const float* __restrict__ out_w,
                                              ushort_t* __restrict__ W1,
                                              ushort_t* __restrict__ W2,
                                              ushort_t* __restrict__ W3) {
    const int idx = blockIdx.x * 256 + threadIdx.x;
    // ---- W1f: 16 ngrps x 52 kfrags x 512 = 425984 elements ----
    if (idx < 425984) {
        const int ngrp = idx / 26624;              // 52*512
        const int kfrag = (idx % 26624) >> 9;
        const int li = idx & 511;
        const int lane = li >> 3, e = li & 7;
        const int n = ngrp * 32 + (lane & 31);
        const int p = kfrag * 16 + (lane >> 5) * 8 + e;
        float acc = 0.f;
        if (p < 784) {
            const int pr = p / 28, pc = p % 28;
#pragma unroll
            for (int dr = 0; dr < 3; ++dr) {
                const int r = pr - dr;
                if (r < 0 || r >= 26) continue;
#pragma unroll
                for (int dc = 0; dc < 3; ++dc) {
                    const int col = pc - dc;
                    if (col < 0 || col >= 26) continue;
                    acc += cw[dr * 3 + dc] * fc1_w[n * 676 + r * 26 + col];
                }
            }
        }
        W1[idx] = f2bf(acc);
    }
    // ---- W2f: 16 ngrps x 32 kfrags x 512 = 262144 ----
    if (idx < 262144) {
        const int ngrp = idx / 16384;              // 32*512
        const int kfrag = (idx % 16384) >> 9;
        const int li = idx & 511;
        const int lane = li >> 3, e = li & 7;
        const int n = ngrp * 32 + (lane & 31);
        const int p = kfrag * 16 + (lane >> 5) * 8 + e;
        W2[idx] = f2bf(fc2_w[n * 512 + p]);
    }
    if (idx < 16 * 512)  W3[idx] = (idx < 10 * 512) ? f2bf(out_w[idx]) : (ushort_t)0;
}

// ================= fully-fused network, v8: small accumulator, big ILP headroom =================
// 512 blocks x 64 batch rows, 1024 threads (16 waves, 4/SIMD). Wave w owns a 64x32 tile
// (n-group w, all 64 rows): acc[2] = 32 AGPRs -> ~96 free VGPRs/wave at 4 waves/SIMD.
// That headroom lets the compiler software-pipeline the per-kfrag W load (L2) and the
// two ds_read_b128 A-fragment reads across the unrolled 4-kfrag step body — the register
// cliff (64 acc + 64 VGPR) of v4/v5 made that impossible and capped MfmaUtil at ~22%.
// Per ksub per wave: 1 coalesced 1KB W load + 2 LDS A reads + 2 MFMAs.
// x: nontemporal fp32 -> bf16 -> double-buffered 8KB LDS (waves 0..7 stage); buffer B
// aliases the first 8KB of hs. hs [64][512] = 64KB. 72KB LDS total.
__global__ __launch_bounds__(1024, 4) void mega8(const float* __restrict__ x,
                                                 const ushort_t* __restrict__ W1,
                                                 const ushort_t* __restrict__ W2,
                                                 const ushort_t* __restrict__ W3,
                                                 const float* __restrict__ b1,
                                                 const float* __restrict__ b2,
                                                 const float* __restrict__ ob,
                                                 float* __restrict__ out) {
    extern __shared__ ushort_t smem[];
    ushort_t* xs0 = smem;                // [64][64]   8 KB  x buffer A (seg-swizzled)
    ushort_t* hs  = smem + 4096;         // [64][512] 64 KB h1/h2 tile; first 8KB = x buffer B

    const int tid = threadIdx.x;
    const int wave = tid >> 6, lane = tid & 63;
    const int r32 = lane & 31, khalf = lane >> 5;
    const bool stager = tid < 512;
    const int xrow = tid >> 3, xoct = tid & 7;          // x staging: 64 rows x 8 octs (tid<512)
    const int m0 = blockIdx.x * 64;
    const size_t ng = wave;                             // this wave's n-group (n = wave*32+r32)

    f32x16 acc[2];                                      // [i = m-frag]; 32 AGPRs
#pragma unroll
    for (int a = 0; a < 2; ++a)
#pragma unroll
        for (int e = 0; e < 16; ++e) acc[a][e] = 0.f;

    // ---- x prefetch (nontemporal fp32), one K-step ahead; 1 row-segment / thread ----
    f32x4 xv0, xv1;
    auto load_x = [&](int ks) {
        const int gc = ks * 64 + xoct * 8;
        if (gc < 784) {
            const f32x4* p = (const f32x4*)&x[(size_t)(m0 + xrow) * 784 + gc];
            xv0 = __builtin_nontemporal_load(p);
            xv1 = __builtin_nontemporal_load(p + 1);
        } else {
            xv0 = (f32x4){0.f, 0.f, 0.f, 0.f};
            xv1 = (f32x4){0.f, 0.f, 0.f, 0.f};
        }
    };
    auto store_x = [&](ushort_t* buf) {
        bf16x8 xv;
        xv[0] = (short)f2bf(xv0.x); xv[1] = (short)f2bf(xv0.y);
        xv[2] = (short)f2bf(xv0.z); xv[3] = (short)f2bf(xv0.w);
        xv[4] = (short)f2bf(xv1.x); xv[5] = (short)f2bf(xv1.y);
        xv[6] = (short)f2bf(xv1.z); xv[7] = (short)f2bf(xv1.w);
        *(bf16x8*)&buf[xrow * 64 + ((xoct ^ (xrow & 7)) * 8)] = xv;
    };

    // h-epilogue: bias+relu -> hs (A-layout, seg' = seg ^ (m&7)); cols = this wave's 32 n
    auto write_h = [&](const float* __restrict__ bias) {
        const int n = wave * 32 + r32;
        const float bb = bias[n];
        const int nseg = n >> 3, nrem = n & 7;
#pragma unroll
        for (int i = 0; i < 2; ++i)
#pragma unroll
            for (int reg = 0; reg < 16; ++reg) {
                const int m = i * 32 + 4 * khalf + (reg & 3) + 8 * (reg >> 2);
                hs[m * 512 + ((nseg ^ (m & 7)) * 8) + nrem] = f2bf(fmaxf(acc[i][reg] + bb, 0.f));
            }
    };

    if (stager) { load_x(0); store_x(xs0); }
    __syncthreads();

    // ---------------- phase 1: K = 832, 12 full steps of BK=64, 1 barrier/step ----------------
    for (int ks = 0; ks < 12; ++ks) {
        if (stager) load_x(ks + 1);                     // next x flies under the MFMAs
        const ushort_t* bufp = (ks & 1) ? hs : xs0;
#pragma unroll
        for (int ksub = 0; ksub < 4; ++ksub) {
            const int kf = ks * 4 + ksub;
            const bf16x8 bw = *(const bf16x8*)&W1[(ng * 52 + kf) * 512 + lane * 8];
            const int q = 2 * ksub + khalf;
            bf16x8 af[2];
#pragma unroll
            for (int i = 0; i < 2; ++i) {
                const int m = i * 32 + r32;
                af[i] = *(const bf16x8*)&bufp[m * 64 + ((q ^ (m & 7)) * 8)];
            }
            __builtin_amdgcn_s_setprio(1);
            acc[0] = __builtin_amdgcn_mfma_f32_32x32x16_bf16(af[0], bw, acc[0], 0, 0, 0);
            acc[1] = __builtin_amdgcn_mfma_f32_32x32x16_bf16(af[1], bw, acc[1], 0, 0, 0);
            __builtin_amdgcn_s_setprio(0);
        }
        if (stager) store_x((ks & 1) ? xs0 : hs);       // fill the other buffer
        __syncthreads();
    }
    // ---- step 12: only kfrag 48 is nonzero (k 768..783 real; 784..831 is zero pad) ----
    {
        const ushort_t* bufp = xs0;                     // ks=12 even -> buffer A
        const bf16x8 bw = *(const bf16x8*)&W1[(ng * 52 + 48) * 512 + lane * 8];
        const int q = khalf;
        bf16x8 af[2];
#pragma unroll
        for (int i = 0; i < 2; ++i) {
            const int m = i * 32 + r32;
            af[i] = *(const bf16x8*)&bufp[m * 64 + ((q ^ (m & 7)) * 8)];
        }
        __builtin_amdgcn_s_setprio(1);
        acc[0] = __builtin_amdgcn_mfma_f32_32x32x16_bf16(af[0], bw, acc[0], 0, 0, 0);
        acc[1] = __builtin_amdgcn_mfma_f32_32x32x16_bf16(af[1], bw, acc[1], 0, 0, 0);
        __builtin_amdgcn_s_setprio(0);
    }
    // no barrier needed: step-12 read xs0 only; h1 writes touch hs, whose last readers
    // (step 11 x-alias reads) finished before the ks=11 barrier.

    // ---- h1 = relu(acc + b1) -> hs ----
    write_h(b1);
#pragma unroll
    for (int a = 0; a < 2; ++a)
#pragma unroll
        for (int e = 0; e < 16; ++e) acc[a][e] = 0.f;
    __syncthreads();

    // ---------------- phase 2: K = 512, no intra-phase barriers ----------------
    for (int ks = 0; ks < 8; ++ks) {
#pragma unroll
        for (int ksub = 0; ksub < 4; ++ksub) {
            const int kf = ks * 4 + ksub;
            const bf16x8 bw = *(const bf16x8*)&W2[(ng * 32 + kf) * 512 + lane * 8];
            const int hq = kf * 2 + khalf;              // 16B-seg index within hs row (0..63)
            bf16x8 af[2];
#pragma unroll
            for (int i = 0; i < 2; ++i) {
                const int m = i * 32 + r32;
                af[i] = *(const bf16x8*)&hs[m * 512 + ((hq ^ (m & 7)) * 8)];
            }
            __builtin_amdgcn_s_setprio(1);
            acc[0] = __builtin_amdgcn_mfma_f32_32x32x16_bf16(af[0], bw, acc[0], 0, 0, 0);
            acc[1] = __builtin_amdgcn_mfma_f32_32x32x16_bf16(af[1], bw, acc[1], 0, 0, 0);
            __builtin_amdgcn_s_setprio(0);
        }
    }
    __syncthreads();                                    // all hs(h1) reads done

    // ---- h2 = relu(acc + b2) -> hs ----
    write_h(b2);
    __syncthreads();

    // ---------------- head: waves 0..3 -> 16 rows each, K=512, direct stores ----------------
    if (wave < 4) {
        const int quad = lane >> 4, l16 = lane & 15;
        const int row = wave * 16 + l16;
        f32x4 hacc = {0.f, 0.f, 0.f, 0.f};
#pragma unroll
        for (int ks = 0; ks < 16; ++ks) {
            const int seg = 4 * ks + quad;
            const bf16x8 a = *(const bf16x8*)&hs[row * 512 + ((seg ^ (row & 7)) * 8)];
            const bf16x8 b = *(const bf16x8*)&W3[l16 * 512 + ks * 32 + quad * 8];
            hacc = __builtin_amdgcn_mfma_f32_16x16x32_bf16(a, b, hacc, 0, 0, 0);
        }
        if (l16 < 10) {
            const float bb = ob[l16];
#pragma unroll
            for (int r = 0; r < 4; ++r)
                out[(size_t)(m0 + wave * 16 + quad * 4 + r) * 10 + l16] = hacc[r] + bb;
        }
    }
}

extern "C" void kernel_launch(void* const* d_in, const int* in_sizes, int n_in,
                              void* d_out, int out_size, void* d_ws, size_t ws_size,
                              hipStream_t stream) {
    const float* x      = (const float*)d_in[0];
    const float* conv_w = (const float*)d_in[1];
    const float* fc1_w  = (const float*)d_in[2];
    const float* fc1_b  = (const float*)d_in[3];
    const float* fc2_w  = (const float*)d_in[4];
    const float* fc2_b  = (const float*)d_in[5];
    const float* out_w  = (const float*)d_in[6];
    const float* out_b  = (const float*)d_in[7];
    float* out = (float*)d_out;

    // workspace: W1f | W2f | W3 (≈1.4 MB total), fragment-major layouts
    ushort_t* W1 = (ushort_t*)d_ws;                    // 16*52*512
    ushort_t* W2 = W1 + 425984;                        // 16*32*512
    ushort_t* W3 = W2 + 262144;                        // 16*512

    prep_w<<<dim3(1664), 256, 0, stream>>>(fc1_w, conv_w, fc2_w, out_w, W1, W2, W3);

    // 512 blocks x 64 rows; 1024 threads (16 waves, 4/SIMD); 72 KB dynamic LDS;
    // acc[2]=32 AGPR -> ~96 free VGPRs/wave for compiler software-pipelining
    mega8<<<dim3(512), 1024, 73728, stream>>>(x, W1, W2, W3, fc1_b, fc2_b, out_b, out);
}

// Round 6
// 211.014 us; speedup vs baseline: 1.2178x; 1.0366x over previous
//
#include <hip/hip_runtime.h>

typedef unsigned short ushort_t;
typedef __attribute__((ext_vector_type(8))) short bf16x8;     // 8 bf16 in 4 VGPRs
typedef __attribute__((ext_vector_type(4))) float f32x4;
typedef __attribute__((ext_vector_type(16))) float f32x16;

__device__ __forceinline__ unsigned short f2bf(float f) {
    union { float f; unsigned u; } v; v.f = f;
    unsigned r = v.u + 0x7FFFu + ((v.u >> 16) & 1u);   // RNE
    return (unsigned short)(r >> 16);
}

// v_cvt_pk_bf16_f32: lo=RNE(a), hi=RNE(b) — bit-identical to f2bf, 1 inst / 2 elems
__device__ __forceinline__ unsigned cvt_pk_bf16(float a, float b) {
    unsigned r;
    asm("v_cvt_pk_bf16_f32 %0, %1, %2" : "=v"(r) : "v"(a), "v"(b));
    return r;
}

// ================= weight prep, fragment-major, coalesced writes =================
// B-fragment layout for v_mfma_f32_32x32x16_bf16: lane = khalf*32 + r32 holds
// W[ngrp*32 + r32][kfrag*16 + khalf*8 .. +8).  Stored as
//   Wf[(ngrp*KFRAGS + kfrag)*512 + lane*8 + e]
// W1eff folds the 3x3 conv into fc1 (p indexes the 28x28 input, zero-padded to 832).
__global__ __launch_bounds__(256) void prep_w(const float* __restrict__ fc1_w,
                                              const float* __restrict__ cw,
                                              const float* __restrict__ fc2_w,
                                              const float* __restrict__ out_w,
                                              ushort_t* __restrict__ W1,
                                              ushort_t* __restrict__ W2,
                                              ushort_t* __restrict__ W3) {
    const int idx = blockIdx.x * 256 + threadIdx.x;
    // ---- W1f: 16 ngrps x 52 kfrags x 512 = 425984 elements ----
    if (idx < 425984) {
        const int ngrp = idx / 26624;              // 52*512
        const int kfrag = (idx % 26624) >> 9;
        const int li = idx & 511;
        const int lane = li >> 3, e = li & 7;
        const int n = ngrp * 32 + (lane & 31);
        const int p = kfrag * 16 + (lane >> 5) * 8 + e;
        float acc = 0.f;
        if (p < 784) {
            const int pr = p / 28, pc = p % 28;
#pragma unroll
            for (int dr = 0; dr < 3; ++dr) {
                const int r = pr - dr;
                if (r < 0 || r >= 26) continue;
#pragma unroll
                for (int dc = 0; dc < 3; ++dc) {
                    const int col = pc - dc;
                    if (col < 0 || col >= 26) continue;
                    acc += cw[dr * 3 + dc] * fc1_w[n * 676 + r * 26 + col];
                }
            }
        }
        W1[idx] = f2bf(acc);
    }
    // ---- W2f: 16 ngrps x 32 kfrags x 512 = 262144 ----
    if (idx < 262144) {
        const int ngrp = idx / 16384;              // 32*512
        const int kfrag = (idx % 16384) >> 9;
        const int li = idx & 511;
        const int lane = li >> 3, e = li & 7;
        const int n = ngrp * 32 + (lane & 31);
        const int p = kfrag * 16 + (lane >> 5) * 8 + e;
        W2[idx] = f2bf(fc2_w[n * 512 + p]);
    }
    if (idx < 16 * 512)  W3[idx] = (idx < 10 * 512) ? f2bf(out_w[idx]) : (ushort_t)0;
}

// ================= fully-fused network, v9r: 8 waves/SIMD (2 blocks/CU) =================
// 512 blocks x 64 batch rows, 1024 threads (16 waves). launch_bounds(1024,8) forces the
// 64-reg/wave budget: acc[2] = 32 AGPR + <=32 VGPR -> TWO blocks co-resident per CU ->
// 8 waves/SIMD, 100% occupancy cap. At 8 waves/SIMD each wave's per-step W-load latency
// (~300-400cy L2) is covered by the other 7 waves' MFMA streams, and the per-step
// barrier only aligns half the CU (blocks destagger independently).
// x staging slimmed to 4 floats/thread (all 1024 threads, packed v_cvt_pk_bf16_f32,
// two dword LDS writes) to fit the register budget.
// x: double-buffered 8KB LDS; buffer B aliases first 8KB of hs. hs [64][512] = 64KB.
// 72KB LDS/block -> 2 blocks/CU.
__global__ __launch_bounds__(1024, 8) void mega9(const float* __restrict__ x,
                                                 const ushort_t* __restrict__ W1,
                                                 const ushort_t* __restrict__ W2,
                                                 const ushort_t* __restrict__ W3,
                                                 const float* __restrict__ b1,
                                                 const float* __restrict__ b2,
                                                 const float* __restrict__ ob,
                                                 float* __restrict__ out) {
    extern __shared__ ushort_t smem[];
    ushort_t* xs0 = smem;                // [64][64]   8 KB  x buffer A (seg-swizzled)
    ushort_t* hs  = smem + 4096;         // [64][512] 64 KB h1/h2 tile; first 8KB = x buffer B

    const int tid = threadIdx.x;
    const int wave = tid >> 6, lane = tid & 63;
    const int r32 = lane & 31, khalf = lane >> 5;
    const int xrow = tid >> 4, xseg = tid & 15;         // x staging: 64 rows x 16 segs(4 cols)
    const int m0 = blockIdx.x * 64;
    const size_t ng = wave;                             // this wave's n-group (n = wave*32+r32)

    f32x16 acc[2];                                      // [i = m-frag]; 32 AGPRs
#pragma unroll
    for (int a = 0; a < 2; ++a)
#pragma unroll
        for (int e = 0; e < 16; ++e) acc[a][e] = 0.f;

    // ---- x prefetch (nontemporal fp32), one K-step ahead; 4 cols of one row / thread ----
    f32x4 xv;
    auto load_x = [&](int ks) {
        const int gc = ks * 64 + xseg * 4;
        if (gc < 784) {
            xv = __builtin_nontemporal_load((const f32x4*)&x[(size_t)(m0 + xrow) * 784 + gc]);
        } else {
            xv = (f32x4){0.f, 0.f, 0.f, 0.f};
        }
    };
    auto store_x = [&](ushort_t* buf) {
        const unsigned lo = cvt_pk_bf16(xv.x, xv.y);
        const unsigned hi = cvt_pk_bf16(xv.z, xv.w);
        unsigned* p = (unsigned*)&buf[xrow * 64 + (((xseg >> 1) ^ (xrow & 7)) * 8) + (xseg & 1) * 4];
        p[0] = lo; p[1] = hi;
    };

    // h-epilogue: bias+relu -> hs (A-layout, seg' = seg ^ (m&7)); cols = this wave's 32 n
    auto write_h = [&](const float* __restrict__ bias) {
        const int n = wave * 32 + r32;
        const float bb = bias[n];
        const int nseg = n >> 3, nrem = n & 7;
#pragma unroll
        for (int i = 0; i < 2; ++i)
#pragma unroll
            for (int reg = 0; reg < 16; ++reg) {
                const int m = i * 32 + 4 * khalf + (reg & 3) + 8 * (reg >> 2);
                hs[m * 512 + ((nseg ^ (m & 7)) * 8) + nrem] = f2bf(fmaxf(acc[i][reg] + bb, 0.f));
            }
    };

    load_x(0);
    store_x(xs0);
    __syncthreads();

    // ---------------- phase 1: K = 832, 12 full steps of BK=64, 1 barrier/step ----------------
    for (int ks = 0; ks < 12; ++ks) {
        load_x(ks + 1);                                 // next x flies under the MFMAs
        const ushort_t* bufp = (ks & 1) ? hs : xs0;
#pragma unroll
        for (int ksub = 0; ksub < 4; ++ksub) {
            const int kf = ks * 4 + ksub;
            const bf16x8 bw = *(const bf16x8*)&W1[(ng * 52 + kf) * 512 + lane * 8];
            const int q = 2 * ksub + khalf;
            bf16x8 af[2];
#pragma unroll
            for (int i = 0; i < 2; ++i) {
                const int m = i * 32 + r32;
                af[i] = *(const bf16x8*)&bufp[m * 64 + ((q ^ (m & 7)) * 8)];
            }
            __builtin_amdgcn_s_setprio(1);
            acc[0] = __builtin_amdgcn_mfma_f32_32x32x16_bf16(af[0], bw, acc[0], 0, 0, 0);
            acc[1] = __builtin_amdgcn_mfma_f32_32x32x16_bf16(af[1], bw, acc[1], 0, 0, 0);
            __builtin_amdgcn_s_setprio(0);
        }
        store_x((ks & 1) ? xs0 : hs);                   // fill the other buffer
        __syncthreads();
    }
    // ---- step 12: only kfrag 48 is nonzero (k 768..783 real; 784..831 is zero pad) ----
    {
        const ushort_t* bufp = xs0;                     // ks=12 even -> buffer A
        const bf16x8 bw = *(const bf16x8*)&W1[(ng * 52 + 48) * 512 + lane * 8];
        const int q = khalf;
        bf16x8 af[2];
#pragma unroll
        for (int i = 0; i < 2; ++i) {
            const int m = i * 32 + r32;
            af[i] = *(const bf16x8*)&bufp[m * 64 + ((q ^ (m & 7)) * 8)];
        }
        __builtin_amdgcn_s_setprio(1);
        acc[0] = __builtin_amdgcn_mfma_f32_32x32x16_bf16(af[0], bw, acc[0], 0, 0, 0);
        acc[1] = __builtin_amdgcn_mfma_f32_32x32x16_bf16(af[1], bw, acc[1], 0, 0, 0);
        __builtin_amdgcn_s_setprio(0);
    }
    // no barrier needed: step-12 read xs0 only; h1 writes touch hs, whose last readers
    // (step 11 x-alias reads) finished before the ks=11 barrier.

    // ---- h1 = relu(acc + b1) -> hs ----
    write_h(b1);
#pragma unroll
    for (int a = 0; a < 2; ++a)
#pragma unroll
        for (int e = 0; e < 16; ++e) acc[a][e] = 0.f;
    __syncthreads();

    // ---------------- phase 2: K = 512, no intra-phase barriers ----------------
    for (int ks = 0; ks < 8; ++ks) {
#pragma unroll
        for (int ksub = 0; ksub < 4; ++ksub) {
            const int kf = ks * 4 + ksub;
            const bf16x8 bw = *(const bf16x8*)&W2[(ng * 32 + kf) * 512 + lane * 8];
            const int hq = kf * 2 + khalf;              // 16B-seg index within hs row (0..63)
            bf16x8 af[2];
#pragma unroll
            for (int i = 0; i < 2; ++i) {
                const int m = i * 32 + r32;
                af[i] = *(const bf16x8*)&hs[m * 512 + ((hq ^ (m & 7)) * 8)];
            }
            __builtin_amdgcn_s_setprio(1);
            acc[0] = __builtin_amdgcn_mfma_f32_32x32x16_bf16(af[0], bw, acc[0], 0, 0, 0);
            acc[1] = __builtin_amdgcn_mfma_f32_32x32x16_bf16(af[1], bw, acc[1], 0, 0, 0);
            __builtin_amdgcn_s_setprio(0);
        }
    }
    __syncthreads();                                    // all hs(h1) reads done

    // ---- h2 = relu(acc + b2) -> hs ----
    write_h(b2);
    __syncthreads();

    // ---------------- head: waves 0..3 -> 16 rows each, K=512, direct stores ----------------
    if (wave < 4) {
        const int quad = lane >> 4, l16 = lane & 15;
        const int row = wave * 16 + l16;
        f32x4 hacc = {0.f, 0.f, 0.f, 0.f};
#pragma unroll
        for (int ks = 0; ks < 16; ++ks) {
            const int seg = 4 * ks + quad;
            const bf16x8 a = *(const bf16x8*)&hs[row * 512 + ((seg ^ (row & 7)) * 8)];
            const bf16x8 b = *(const bf16x8*)&W3[l16 * 512 + ks * 32 + quad * 8];
            hacc = __builtin_amdgcn_mfma_f32_16x16x32_bf16(a, b, hacc, 0, 0, 0);
        }
        if (l16 < 10) {
            const float bb = ob[l16];
#pragma unroll
            for (int r = 0; r < 4; ++r)
                out[(size_t)(m0 + wave * 16 + quad * 4 + r) * 10 + l16] = hacc[r] + bb;
        }
    }
}

extern "C" void kernel_launch(void* const* d_in, const int* in_sizes, int n_in,
                              void* d_out, int out_size, void* d_ws, size_t ws_size,
                              hipStream_t stream) {
    const float* x      = (const float*)d_in[0];
    const float* conv_w = (const float*)d_in[1];
    const float* fc1_w  = (const float*)d_in[2];
    const float* fc1_b  = (const float*)d_in[3];
    const float* fc2_w  = (const float*)d_in[4];
    const float* fc2_b  = (const float*)d_in[5];
    const float* out_w  = (const float*)d_in[6];
    const float* out_b  = (const float*)d_in[7];
    float* out = (float*)d_out;

    // workspace: W1f | W2f | W3 (≈1.4 MB total), fragment-major layouts
    ushort_t* W1 = (ushort_t*)d_ws;                    // 16*52*512
    ushort_t* W2 = W1 + 425984;                        // 16*32*512
    ushort_t* W3 = W2 + 262144;                        // 16*512

    prep_w<<<dim3(1664), 256, 0, stream>>>(fc1_w, conv_w, fc2_w, out_w, W1, W2, W3);

    // 512 blocks x 64 rows; 1024 threads (16 waves); 72 KB dynamic LDS;
    // launch_bounds(1024,8): 64-reg budget -> 2 blocks/CU -> 8 waves/SIMD
    mega9<<<dim3(512), 1024, 73728, stream>>>(x, W1, W2, W3, fc1_b, fc2_b, out_b, out);
}